// Round 2
// baseline (276.745 us; speedup 1.0000x reference)
//
#include <hip/hip_runtime.h>
#include <math.h>

#define TOKS 256   // tokens per block (== blockDim.x)
#define NEXP 256   // experts
#define NGRP 8     // groups
// group size 32, topk-group 4, top-k 8

// f64 sigmoid, mirrors np: 1/(1+exp(-x)). |logit| < ~6 so no overflow concern.
__device__ __forceinline__ double sigmoid64(float xf) {
    double x = (double)xf;
    return 1.0 / (1.0 + exp(-x));
}

// branchless sorted-descending insert into (v0..v7, i0..i7), gated on beating v7.
// strict > keeps earlier-inserted-first stability on exact ties (measure-zero in f64).
#define INSERT(cc, ee) do {                                              \
    double _c = (cc); int _e = (ee);                                     \
    if (_c > v7) {                                                       \
        bool _b0=_c>v0,_b1=_c>v1,_b2=_c>v2,_b3=_c>v3,_b4=_c>v4,_b5=_c>v5,_b6=_c>v6; \
        v7 = _b6 ? v6 : _c;              i7 = _b6 ? i6 : _e;             \
        v6 = _b5 ? v5 : (_b6 ? _c : v6); i6 = _b5 ? i5 : (_b6 ? _e : i6);\
        v5 = _b4 ? v4 : (_b5 ? _c : v5); i5 = _b4 ? i4 : (_b5 ? _e : i5);\
        v4 = _b3 ? v3 : (_b4 ? _c : v4); i4 = _b3 ? i3 : (_b4 ? _e : i4);\
        v3 = _b2 ? v2 : (_b3 ? _c : v3); i3 = _b2 ? i2 : (_b3 ? _e : i3);\
        v2 = _b1 ? v1 : (_b2 ? _c : v2); i2 = _b1 ? i1 : (_b2 ? _e : i2);\
        v1 = _b0 ? v0 : (_b1 ? _c : v1); i1 = _b0 ? i0 : (_b1 ? _e : i1);\
        v0 = _b0 ? _c : v0;              i0 = _b0 ? _e : i0;             \
    } } while (0)

__global__ __launch_bounds__(TOKS, 3)
void noauxtc_router_kernel(const float* __restrict__ logits,
                           const float* __restrict__ bias,
                           float* __restrict__ out,   // [T*8] weights f32, then [T*8] ids as f32
                           int T)
{
    // one group-chunk: 256 tokens x 32 experts, xor-swizzled float4 layout.
    __shared__ float4 chunk4[TOKS * 8];                 // 32 KiB
    __shared__ __align__(16) float bias_sh[NEXP];       // 1 KiB (float4-readable, uniform idx)
    __shared__ float bias_rot[NEXP + NGRP];             // +1 pad/group: divergent-group reads conflict-free

    const int tid   = threadIdx.x;
    const int tok0  = blockIdx.x * TOKS;
    const int token = tok0 + tid;

    {
        float b = bias[tid];                // blockDim == NEXP
        bias_sh[tid] = b;
        bias_rot[tid + (tid >> 5)] = b;     // index e + group(e)
    }

    const float4* lg4 = (const float4*)logits;   // token row = 64 float4
    const float4* b4  = (const float4*)bias_sh;

    // ---------------- pass A: group scores (top-2 sum of corrected scores), f64 ----------------
    double gs0=0.,gs1=0.,gs2=0.,gs3=0.,gs4=0.,gs5=0.,gs6=0.,gs7=0.;

    for (int g = 0; g < NGRP; ++g) {
        __syncthreads();   // protect chunk4 reuse
        // stage: 2048 float4 (256 tok x 8 float4), 8 per thread, coalesced 128B runs
        #pragma unroll
        for (int j = 0; j < 8; ++j) {
            int row = j*32 + (tid >> 3);
            int q   = tid & 7;
            float4 x = lg4[(size_t)(tok0 + row)*64 + g*8 + q];
            chunk4[row*8 + (q ^ (row & 7))] = x;   // xor swizzle -> conflict-free b128 r/w
        }
        __syncthreads();

        double a1 = -1.0e300, a2 = -1.0e300;
        #pragma unroll
        for (int q = 0; q < 8; ++q) {
            float4 x  = chunk4[tid*8 + (q ^ (tid & 7))];
            float4 bb = b4[g*8 + q];                  // uniform -> LDS broadcast
            double c;
            c = sigmoid64(x.x) + (double)bb.x; a2 = fmax(a2, fmin(a1,c)); a1 = fmax(a1,c);
            c = sigmoid64(x.y) + (double)bb.y; a2 = fmax(a2, fmin(a1,c)); a1 = fmax(a1,c);
            c = sigmoid64(x.z) + (double)bb.z; a2 = fmax(a2, fmin(a1,c)); a1 = fmax(a1,c);
            c = sigmoid64(x.w) + (double)bb.w; a2 = fmax(a2, fmin(a1,c)); a1 = fmax(a1,c);
        }
        double sc = a1 + a2;
        // rotate so indices stay static (no dynamic register-array writes)
        gs0=gs1; gs1=gs2; gs2=gs3; gs3=gs4; gs4=gs5; gs5=gs6; gs6=gs7; gs7=sc;
    }

    // ---------------- top-4 groups by rank counting (lower index wins ties) ----------------
    double gsA[8] = {gs0,gs1,gs2,gs3,gs4,gs5,gs6,gs7};
    int gpack = 0;   // byte r = group with rank r (r<4)
    #pragma unroll
    for (int g = 0; g < 8; ++g) {
        int r = 0;
        #pragma unroll
        for (int h = 0; h < 8; ++h) {
            if (h == g) continue;
            bool beat = (h < g) ? (gsA[h] >= gsA[g]) : (gsA[h] > gsA[g]);
            r += beat ? 1 : 0;
        }
        gpack |= (r < 4) ? (g << (8*r)) : 0;
    }

    // ---------------- pass B: top-8 experts over 4 selected groups, f64 ----------------
    double v0=-1e300,v1=-1e300,v2=-1e300,v3=-1e300,v4=-1e300,v5=-1e300,v6=-1e300,v7=-1e300;
    int   i0=0,i1=0,i2=0,i3=0,i4=0,i5=0,i6=0,i7=0;

    #pragma unroll 1
    for (int k = 0; k < 4; ++k) {
        int g = (gpack >> (8*k)) & 0xff;                 // per-lane divergent group id
        const float4* rp = lg4 + (size_t)token*64 + g*8; // re-read from L2/L3 (just-fetched)
        #pragma unroll
        for (int q = 0; q < 8; ++q) {
            float4 x = rp[q];
            int eb = g*32 + q*4;   // expert index base
            int ro = eb + g;       // bias_rot index base (e + group)
            double c;
            c = sigmoid64(x.x) + (double)bias_rot[ro+0]; INSERT(c, eb+0);
            c = sigmoid64(x.y) + (double)bias_rot[ro+1]; INSERT(c, eb+1);
            c = sigmoid64(x.z) + (double)bias_rot[ro+2]; INSERT(c, eb+2);
            c = sigmoid64(x.w) + (double)bias_rot[ro+3]; INSERT(c, eb+3);
        }
    }

    // ---------------- epilogue: uncorrected weights, renorm, x2.5, store ----------------
    double w0 = v0 - (double)bias_rot[i0 + (i0>>5)];
    double w1 = v1 - (double)bias_rot[i1 + (i1>>5)];
    double w2 = v2 - (double)bias_rot[i2 + (i2>>5)];
    double w3 = v3 - (double)bias_rot[i3 + (i3>>5)];
    double w4 = v4 - (double)bias_rot[i4 + (i4>>5)];
    double w5 = v5 - (double)bias_rot[i5 + (i5>>5)];
    double w6 = v6 - (double)bias_rot[i6 + (i6>>5)];
    double w7 = v7 - (double)bias_rot[i7 + (i7>>5)];
    double sum = ((w0+w1)+(w2+w3)) + ((w4+w5)+(w6+w7));
    double scl = 2.5 / (sum + 1e-20);

    float4 oa, ob;
    oa.x = (float)(w0*scl); oa.y = (float)(w1*scl); oa.z = (float)(w2*scl); oa.w = (float)(w3*scl);
    ob.x = (float)(w4*scl); ob.y = (float)(w5*scl); ob.z = (float)(w6*scl); ob.w = (float)(w7*scl);
    *(float4*)(out + (size_t)token*8)     = oa;
    *(float4*)(out + (size_t)token*8 + 4) = ob;

    float* oid = out + (size_t)T*8;
    float4 ia, ib;
    ia.x = (float)i0; ia.y = (float)i1; ia.z = (float)i2; ia.w = (float)i3;
    ib.x = (float)i4; ib.y = (float)i5; ib.z = (float)i6; ib.w = (float)i7;
    *(float4*)(oid + (size_t)token*8)     = ia;
    *(float4*)(oid + (size_t)token*8 + 4) = ib;
}

extern "C" void kernel_launch(void* const* d_in, const int* in_sizes, int n_in,
                              void* d_out, int out_size, void* d_ws, size_t ws_size,
                              hipStream_t stream) {
    const float* logits = (const float*)d_in[0];
    const float* bias   = (const float*)d_in[1];
    float* out = (float*)d_out;
    int T = in_sizes[0] / NEXP;        // 131072
    int nblocks = T / TOKS;            // 512 (T is a multiple of 256)
    noauxtc_router_kernel<<<nblocks, TOKS, 0, stream>>>(logits, bias, out, T);
}

// Round 3
// 257.057 us; speedup vs baseline: 1.0766x; 1.0766x over previous
//
#include <hip/hip_runtime.h>
#include <math.h>

#define TOKS 128   // tokens per block (== blockDim.x); 17 KiB LDS -> ~4 blocks/CU
#define NEXP 256
#define NGRP 8
// margins: f32 score err <= ~4e-7 (hw exp 1ulp + __fdividef 2.5ulp + add); 2.5x safety
#define EPS_S 2.0e-6f   // single-score compares (expert top-10 adjacency)
#define EPS_G 4.0e-6f   // group-sum compares (4th vs 5th group)

// ---- fast f32 sigmoid: hw v_exp_f32 + v_rcp (total err <= ~4e-7 on the score) ----
__device__ __forceinline__ float fsigmoid(float x) {
    float e = __expf(-x);
    return __fdividef(1.0f, 1.0f + e);
}

// ---- cheap near-correctly-rounded f64 sigmoid (~1e-15 rel): Taylor exp + NR div ----
__device__ __forceinline__ double dsigmoid(float xf) {
    xf = fminf(fmaxf(xf, -500.0f), 500.0f);          // keep 2^n exponent in range
    double x = (double)xf;
    double t = x * -1.4426950408889634074;           // -x*log2(e)
    double n = floor(t + 0.5);
    int ni = (int)n;
    double u = (t - n) * 0.69314718055994530942;     // |u| <= 0.3466
    double p = 2.08767569878680990e-9;               // 1/12!
    p = fma(p, u, 2.50521083854417188e-8);
    p = fma(p, u, 2.75573192239858907e-7);
    p = fma(p, u, 2.75573192239858883e-6);
    p = fma(p, u, 2.48015873015873016e-5);
    p = fma(p, u, 1.98412698412698413e-4);
    p = fma(p, u, 1.38888888888888889e-3);
    p = fma(p, u, 8.33333333333333333e-3);
    p = fma(p, u, 4.16666666666666667e-2);
    p = fma(p, u, 1.66666666666666667e-1);
    p = fma(p, u, 0.5);
    p = fma(p, u, 1.0);
    p = fma(p, u, 1.0);                              // e^u
    double sc = __longlong_as_double((long long)(1023 + ni) << 52);  // 2^ni
    double e = p * sc;                               // exp(-x)
    double w = 1.0 + e;
    double y = (double)__fdividef(1.0f, (float)w);   // ~2.5ulp f32 seed
    y = fma(y, fma(-w, y, 1.0), y);                  // NR -> ~1e-14
    y = fma(y, fma(-w, y, 1.0), y);                  // NR -> full f64
    return y;
}

// branchless sorted-descending top-10 insert, gated on beating v9.
#define INSERT10(cc, ee) do {                                            \
    float _c = (cc); int _e = (ee);                                      \
    if (_c > v9) {                                                       \
        bool _q0=_c>v0,_q1=_c>v1,_q2=_c>v2,_q3=_c>v3,_q4=_c>v4,         \
             _q5=_c>v5,_q6=_c>v6,_q7=_c>v7,_q8=_c>v8;                    \
        v9 = _q8 ? v8 : _c;              i9 = _q8 ? i8 : _e;             \
        v8 = _q7 ? v7 : (_q8 ? _c : v8); i8 = _q7 ? i7 : (_q8 ? _e : i8);\
        v7 = _q6 ? v6 : (_q7 ? _c : v7); i7 = _q6 ? i6 : (_q7 ? _e : i7);\
        v6 = _q5 ? v5 : (_q6 ? _c : v6); i6 = _q5 ? i5 : (_q6 ? _e : i6);\
        v5 = _q4 ? v4 : (_q5 ? _c : v5); i5 = _q4 ? i4 : (_q5 ? _e : i5);\
        v4 = _q3 ? v3 : (_q4 ? _c : v4); i4 = _q3 ? i3 : (_q4 ? _e : i4);\
        v3 = _q2 ? v2 : (_q3 ? _c : v3); i3 = _q2 ? i2 : (_q3 ? _e : i3);\
        v2 = _q1 ? v1 : (_q2 ? _c : v2); i2 = _q1 ? i1 : (_q2 ? _e : i2);\
        v1 = _q0 ? v0 : (_q1 ? _c : v1); i1 = _q0 ? i0 : (_q1 ? _e : i1);\
        v0 = _q0 ? _c : v0;              i0 = _q0 ? _e : i0;             \
    } } while (0)

#define TOP2(c) do { a2 = fmax(a2, fmin(a1,(c))); a1 = fmax(a1,(c)); } while (0)

__global__ __launch_bounds__(TOKS, 2)
void noauxtc_router_kernel(const float* __restrict__ logits,
                           const float* __restrict__ bias,
                           float* __restrict__ out,   // [T*8] weights f32, then [T*8] ids as f32
                           int T)
{
    __shared__ float4 chunk4[TOKS * 8];                 // 16 KiB: 128 tok x 32 exp, xor-swizzled
    __shared__ __align__(16) float bias_sh[NEXP];       // float4-readable, uniform idx
    __shared__ float bias_rot[NEXP + NGRP];             // +1 pad/group: divergent reads conflict-free

    const int tid   = threadIdx.x;
    const int tok0  = blockIdx.x * TOKS;
    const int token = tok0 + tid;

    for (int i = tid; i < NEXP; i += TOKS) {
        float b = bias[i];
        bias_sh[i] = b;
        bias_rot[i + (i >> 5)] = b;     // index e + group(e)
    }   // first g-iter's post-staging barrier covers these writes

    const float4* lg4   = (const float4*)logits;        // token row = 64 float4
    const float4* bias4 = (const float4*)bias_sh;

    // ---------------- pass A (f32): group scores = top-2 sum of corrected scores ----------------
    float gs0=0.f,gs1=0.f,gs2=0.f,gs3=0.f,gs4=0.f,gs5=0.f,gs6=0.f,gs7=0.f;

    #pragma unroll 1
    for (int g = 0; g < NGRP; ++g) {
        __syncthreads();
        #pragma unroll
        for (int j = 0; j < 8; ++j) {           // 1024 float4, 8/thread, coalesced 128B runs
            int row = j*16 + (tid >> 3);
            int q   = tid & 7;
            float4 x = lg4[(size_t)(tok0 + row)*64 + g*8 + q];
            chunk4[row*8 + (q ^ (row & 7))] = x;
        }
        __syncthreads();
        float a1 = -3.0e38f, a2 = -3.0e38f;
        #pragma unroll
        for (int q = 0; q < 8; ++q) {
            float4 x  = chunk4[tid*8 + (q ^ (tid & 7))];
            float4 bb = bias4[g*8 + q];         // uniform -> LDS broadcast
            float c;
            c = fsigmoid(x.x) + bb.x; a2 = fmaxf(a2, fminf(a1,c)); a1 = fmaxf(a1,c);
            c = fsigmoid(x.y) + bb.y; a2 = fmaxf(a2, fminf(a1,c)); a1 = fmaxf(a1,c);
            c = fsigmoid(x.z) + bb.z; a2 = fmaxf(a2, fminf(a1,c)); a1 = fmaxf(a1,c);
            c = fsigmoid(x.w) + bb.w; a2 = fmaxf(a2, fminf(a1,c)); a1 = fmaxf(a1,c);
        }
        float sc = a1 + a2;
        gs0=gs1; gs1=gs2; gs2=gs3; gs3=gs4; gs4=gs5; gs5=gs6; gs6=gs7; gs7=sc;
    }
    float gsA[8] = {gs0,gs1,gs2,gs3,gs4,gs5,gs6,gs7};

    // ---------------- group top-4 (rank counting; lower index wins) + margin ----------------
    int gpack = 0; float val4 = 0.f, val5 = 0.f;
    #pragma unroll
    for (int g = 0; g < 8; ++g) {
        int r = 0;
        #pragma unroll
        for (int h = 0; h < 8; ++h) {
            if (h == g) continue;
            bool beat = (h < g) ? (gsA[h] >= gsA[g]) : (gsA[h] > gsA[g]);
            r += beat ? 1 : 0;
        }
        gpack |= (r < 4) ? (g << (8*r)) : 0;
        val4 = (r == 3) ? gsA[g] : val4;
        val5 = (r == 4) ? gsA[g] : val5;
    }

    // ---- flagA: 4th vs 5th group ambiguous (~1e-4 of tokens) -> f64 the boundary band ----
    if (__builtin_expect(val4 - val5 < EPS_G, 0)) {
        double gsd[8];
        #pragma unroll
        for (int g = 0; g < 8; ++g) {
            float gf = gsA[g];
            if (gf >= val5 - EPS_G && gf <= val4 + EPS_G) {
                double a1 = -1.0e300, a2 = -1.0e300;
                const float4* rp = lg4 + (size_t)token*64 + g*8;
                #pragma unroll 1
                for (int q = 0; q < 8; ++q) {
                    float4 x = rp[q];
                    int ro = g*32 + q*4 + g;
                    double c;
                    c = dsigmoid(x.x) + (double)bias_rot[ro+0]; TOP2(c);
                    c = dsigmoid(x.y) + (double)bias_rot[ro+1]; TOP2(c);
                    c = dsigmoid(x.z) + (double)bias_rot[ro+2]; TOP2(c);
                    c = dsigmoid(x.w) + (double)bias_rot[ro+3]; TOP2(c);
                }
                gsd[g] = a1 + a2;
            } else {
                gsd[g] = (double)gf;
            }
        }
        int gp = 0;
        #pragma unroll
        for (int g = 0; g < 8; ++g) {
            int r = 0;
            #pragma unroll
            for (int h = 0; h < 8; ++h) {
                if (h == g) continue;
                bool beat = (h < g) ? (gsd[h] >= gsd[g]) : (gsd[h] > gsd[g]);
                r += beat ? 1 : 0;
            }
            gp |= (r < 4) ? (g << (8*r)) : 0;
        }
        gpack = gp;
    }

    // ---------------- pass B (f32): top-10 experts over 4 selected groups ----------------
    float v0=-3e38f,v1=-3e38f,v2=-3e38f,v3=-3e38f,v4=-3e38f,
          v5=-3e38f,v6=-3e38f,v7=-3e38f,v8=-3e38f,v9=-3e38f;
    int   i0=0,i1=0,i2=0,i3=0,i4=0,i5=0,i6=0,i7=0,i8=0,i9=0;

    #pragma unroll 1
    for (int k = 0; k < 4; ++k) {
        int g = (gpack >> (8*k)) & 0xff;
        const float4* rp = lg4 + (size_t)token*64 + g*8;   // L2/L3-hot re-read
        #pragma unroll
        for (int q = 0; q < 8; ++q) {
            float4 x = rp[q];
            int eb = g*32 + q*4;
            int ro = eb + g;
            float c;
            c = fsigmoid(x.x) + bias_rot[ro+0]; INSERT10(c, eb+0);
            c = fsigmoid(x.y) + bias_rot[ro+1]; INSERT10(c, eb+1);
            c = fsigmoid(x.z) + bias_rot[ro+2]; INSERT10(c, eb+2);
            c = fsigmoid(x.w) + bias_rot[ro+3]; INSERT10(c, eb+3);
        }
    }

    // ---------------- fast-path result ----------------
    float w0 = v0 - bias_rot[i0 + (i0>>5)];
    float w1 = v1 - bias_rot[i1 + (i1>>5)];
    float w2 = v2 - bias_rot[i2 + (i2>>5)];
    float w3 = v3 - bias_rot[i3 + (i3>>5)];
    float w4 = v4 - bias_rot[i4 + (i4>>5)];
    float w5 = v5 - bias_rot[i5 + (i5>>5)];
    float w6 = v6 - bias_rot[i6 + (i6>>5)];
    float w7 = v7 - bias_rot[i7 + (i7>>5)];
    int o0=i0,o1=i1,o2=i2,o3=i3,o4=i4,o5=i5,o6=i6,o7=i7;

    // ---- flagB: any adjacent top-10 margin ambiguous (~0.2% of tokens) -> f64 refine 10 ----
    bool flagB = ((v0-v1) < EPS_S) | ((v1-v2) < EPS_S) | ((v2-v3) < EPS_S) |
                 ((v3-v4) < EPS_S) | ((v4-v5) < EPS_S) | ((v5-v6) < EPS_S) |
                 ((v6-v7) < EPS_S) | ((v7-v8) < EPS_S) | ((v8-v9) < EPS_S);
    if (__builtin_expect(flagB, 0)) {
        double cv[10]; int ci[10] = {i0,i1,i2,i3,i4,i5,i6,i7,i8,i9};
        #pragma unroll
        for (int k = 0; k < 10; ++k) {
            int e = ci[k];
            float lx = logits[(size_t)token*256 + e];
            cv[k] = dsigmoid(lx) + (double)bias_rot[e + (e>>5)];
        }
        // stable total order: value desc, index asc (np top_k semantics); 45-CE bubble
        #pragma unroll
        for (int a = 0; a < 9; ++a) {
            #pragma unroll
            for (int b = 0; b < 9 - a; ++b) {
                bool sw = (cv[b] < cv[b+1]) || ((cv[b] == cv[b+1]) & (ci[b] > ci[b+1]));
                double t0 = sw ? cv[b+1] : cv[b], t1 = sw ? cv[b] : cv[b+1];
                int    u0 = sw ? ci[b+1] : ci[b], u1 = sw ? ci[b] : ci[b+1];
                cv[b] = t0; cv[b+1] = t1; ci[b] = u0; ci[b+1] = u1;
            }
        }
        o0=ci[0]; w0=(float)(cv[0]-(double)bias_rot[ci[0]+(ci[0]>>5)]);
        o1=ci[1]; w1=(float)(cv[1]-(double)bias_rot[ci[1]+(ci[1]>>5)]);
        o2=ci[2]; w2=(float)(cv[2]-(double)bias_rot[ci[2]+(ci[2]>>5)]);
        o3=ci[3]; w3=(float)(cv[3]-(double)bias_rot[ci[3]+(ci[3]>>5)]);
        o4=ci[4]; w4=(float)(cv[4]-(double)bias_rot[ci[4]+(ci[4]>>5)]);
        o5=ci[5]; w5=(float)(cv[5]-(double)bias_rot[ci[5]+(ci[5]>>5)]);
        o6=ci[6]; w6=(float)(cv[6]-(double)bias_rot[ci[6]+(ci[6]>>5)]);
        o7=ci[7]; w7=(float)(cv[7]-(double)bias_rot[ci[7]+(ci[7]>>5)]);
    }

    // ---------------- epilogue: renorm, x2.5, store ----------------
    float sum = ((w0+w1)+(w2+w3)) + ((w4+w5)+(w6+w7));
    float scl = 2.5f / (sum + 1e-20f);

    float4 oa, ob;
    oa.x = w0*scl; oa.y = w1*scl; oa.z = w2*scl; oa.w = w3*scl;
    ob.x = w4*scl; ob.y = w5*scl; ob.z = w6*scl; ob.w = w7*scl;
    *(float4*)(out + (size_t)token*8)     = oa;
    *(float4*)(out + (size_t)token*8 + 4) = ob;

    float* oid = out + (size_t)T*8;
    float4 ia, ib;
    ia.x = (float)o0; ia.y = (float)o1; ia.z = (float)o2; ia.w = (float)o3;
    ib.x = (float)o4; ib.y = (float)o5; ib.z = (float)o6; ib.w = (float)o7;
    *(float4*)(oid + (size_t)token*8)     = ia;
    *(float4*)(oid + (size_t)token*8 + 4) = ib;
}

extern "C" void kernel_launch(void* const* d_in, const int* in_sizes, int n_in,
                              void* d_out, int out_size, void* d_ws, size_t ws_size,
                              hipStream_t stream) {
    const float* logits = (const float*)d_in[0];
    const float* bias   = (const float*)d_in[1];
    float* out = (float*)d_out;
    int T = in_sizes[0] / NEXP;        // 131072
    int nblocks = T / TOKS;            // 1024
    noauxtc_router_kernel<<<nblocks, TOKS, 0, stream>>>(logits, bias, out, T);
}